// Round 7
// baseline (1745.600 us; speedup 1.0000x reference)
//
#include <hip/hip_runtime.h>
#include <cfloat>
#include <cstdint>

#define HEADS 4
#define HIDC 128
#define HC 512
#define NEG 0.2f

typedef _Float16 half8 __attribute__((ext_vector_type(8)));
typedef float floatx4 __attribute__((ext_vector_type(4)));
typedef unsigned int uint4v __attribute__((ext_vector_type(4)));

// ---------------- f16 MFMA GEMM ----------------
// C = A[Mp,K] @ Bt[N,K]^T. 128x128 tile, BK=64, 4 waves 2x2, each 64x64 via
// 4x4 mfma_f32_16x16x32_f16 (2 K-slices per iter). XOR-swizzled LDS (linear
// global_load_lds dest + pre-swizzled global source col, same XOR on ds_read).
// XCD-chunk bijective blockIdx swizzle. Nontemporal C stores (C is consumed
// much later / once -> don't evict h from L2).
// If atts != null (N==512): fuse a_src/a_dst per-head dot into epilogue.
__global__ __launch_bounds__(256) void mfma_gemm(
    const _Float16* __restrict__ A,   // [Mp][K]
    const _Float16* __restrict__ Bt,  // [N][K]
    _Float16* __restrict__ Ch,        // [Mp][N] f16 out (or null)
    float* __restrict__ Cf,           // [M][N] fp32 out (or null)
    const float* __restrict__ bias,   // [N] (with Cf) or null
    const float* __restrict__ atts,   // [HEADS][128] or null
    const float* __restrict__ attd,
    float* __restrict__ a_src,        // [M][4]
    float* __restrict__ a_dst,
    int M, int N, int K)
{
    __shared__ __align__(16) _Float16 As[128 * 64];
    __shared__ __align__(16) _Float16 Bs[128 * 64];

    // ---- bijective XCD swizzle ----
    const int nwg = gridDim.x * gridDim.y;
    int lin = blockIdx.y * gridDim.x + blockIdx.x;
    {
        const int q = nwg >> 3, r = nwg & 7;
        const int xcd = lin & 7, pos = lin >> 3;
        lin = (xcd < r ? xcd * (q + 1) : r * (q + 1) + (xcd - r) * q) + pos;
    }
    const int bx = lin % gridDim.x;
    const int by = lin / gridDim.x;

    const int tid = threadIdx.x;
    const int w = tid >> 6;
    const int lane = tid & 63;
    const int wr = (w >> 1) * 64;
    const int wc = (w & 1) * 64;

    const int rowBase = by * 128;
    const int colBase = bx * 128;

    // staging: per wave 4 stripes of 8 rows (A and B), pre-swizzled source col
    const int strow = lane >> 3;                        // 0..7
    const int sColSw = ((lane & 7) ^ strow) * 8;        // swizzled elem col 0..56

    const _Float16* gaP[4];
    const _Float16* gbP[4];
    _Float16* lA[4];
    _Float16* lB[4];
#pragma unroll
    for (int c = 0; c < 4; c++) {
        const int rr = c * 32 + w * 8;                  // stripe base row
        gaP[c] = A + (size_t)(rowBase + rr + strow) * K + sColSw;
        gbP[c] = Bt + (size_t)(colBase + rr + strow) * K + sColSw;
        lA[c] = &As[rr * 64];
        lB[c] = &Bs[rr * 64];
    }

    floatx4 acc[4][4];
#pragma unroll
    for (int i = 0; i < 4; i++)
#pragma unroll
        for (int j = 0; j < 4; j++) acc[i][j] = {0.f, 0.f, 0.f, 0.f};

    const int q16 = lane >> 4;
    const int l16 = lane & 15;

    for (int k0 = 0; k0 < K; k0 += 64) {
#pragma unroll
        for (int c = 0; c < 4; c++) {
            __builtin_amdgcn_global_load_lds(
                (const __attribute__((address_space(1))) unsigned int*)gaP[c],
                (__attribute__((address_space(3))) unsigned int*)lA[c], 16, 0, 0);
            __builtin_amdgcn_global_load_lds(
                (const __attribute__((address_space(1))) unsigned int*)gbP[c],
                (__attribute__((address_space(3))) unsigned int*)lB[c], 16, 0, 0);
            gaP[c] += 64;
            gbP[c] += 64;
        }
        __syncthreads();

#pragma unroll
        for (int s = 0; s < 2; s++) {
            half8 af[4], bf[4];
#pragma unroll
            for (int i = 0; i < 4; i++) {
                const int r = wr + i * 16 + l16;
                af[i] = *(const half8*)&As[r * 64 + (((s * 4 + q16) ^ (r & 7)) * 8)];
            }
#pragma unroll
            for (int j = 0; j < 4; j++) {
                const int r = wc + j * 16 + l16;
                bf[j] = *(const half8*)&Bs[r * 64 + (((s * 4 + q16) ^ (r & 7)) * 8)];
            }
#pragma unroll
            for (int i = 0; i < 4; i++)
#pragma unroll
                for (int j = 0; j < 4; j++)
                    acc[i][j] = __builtin_amdgcn_mfma_f32_16x16x32_f16(af[i], bf[j], acc[i][j], 0, 0, 0);
        }
        __syncthreads();
    }

    // ---- C stores (C/D layout: col=l16, row=q16*4+r), nontemporal ----
    if (Ch) {
#pragma unroll
        for (int i = 0; i < 4; i++)
#pragma unroll
            for (int j = 0; j < 4; j++) {
                const int col = colBase + wc + j * 16 + l16;
#pragma unroll
                for (int r = 0; r < 4; r++) {
                    const int row = rowBase + wr + i * 16 + q16 * 4 + r;
                    if (row < M)
                        __builtin_nontemporal_store((_Float16)acc[i][j][r],
                                                    &Ch[(size_t)row * N + col]);
                }
            }
    }
    if (Cf) {
#pragma unroll
        for (int i = 0; i < 4; i++)
#pragma unroll
            for (int j = 0; j < 4; j++) {
                const int col = colBase + wc + j * 16 + l16;
                const float bb = bias ? bias[col] : 0.f;
#pragma unroll
                for (int r = 0; r < 4; r++) {
                    const int row = rowBase + wr + i * 16 + q16 * 4 + r;
                    if (row < M)
                        __builtin_nontemporal_store(acc[i][j][r] + bb,
                                                    &Cf[(size_t)row * N + col]);
                }
            }
    }

    // ---- fused attention coefficients (layers only) ----
    if (atts) {
        float* ps = (float*)As;        // [2][128]
        float* pd = ps + 256;          // [2][128]
        const int head = bx;
        float as[4], ad[4];
#pragma unroll
        for (int j = 0; j < 4; j++) {
            const int cl = wc + j * 16 + l16;
            as[j] = atts[head * HIDC + cl];
            ad[j] = attd[head * HIDC + cl];
        }
#pragma unroll
        for (int i = 0; i < 4; i++) {
#pragma unroll
            for (int r = 0; r < 4; r++) {
                float s_ = acc[i][0][r] * as[0] + acc[i][1][r] * as[1]
                         + acc[i][2][r] * as[2] + acc[i][3][r] * as[3];
                float d_ = acc[i][0][r] * ad[0] + acc[i][1][r] * ad[1]
                         + acc[i][2][r] * ad[2] + acc[i][3][r] * ad[3];
#pragma unroll
                for (int mk = 1; mk <= 8; mk <<= 1) {
                    s_ += __shfl_xor(s_, mk);
                    d_ += __shfl_xor(d_, mk);
                }
                if (l16 == 0) {
                    const int rloc = wr + i * 16 + q16 * 4 + r;
                    ps[(wc >> 6) * 128 + rloc] = s_;
                    pd[(wc >> 6) * 128 + rloc] = d_;
                }
            }
        }
        __syncthreads();
        if (tid < 128) {
            const int row = rowBase + tid;
            if (row < M) {
                a_src[(size_t)row * 4 + head] = ps[tid] + ps[128 + tid];
                a_dst[(size_t)row * 4 + head] = pd[tid] + pd[128 + tid];
            }
        }
    }
}

// ---------------- dtype conversion ----------------
__global__ void convert_x_kernel(const float* __restrict__ x, _Float16* __restrict__ o, size_t nquads)
{
    size_t i = (size_t)blockIdx.x * blockDim.x + threadIdx.x;
    if (i < nquads) {
        float4 v = *(const float4*)(x + i * 4);
        _Float16* p = o + i * 4;
        p[0] = (_Float16)v.x; p[1] = (_Float16)v.y;
        p[2] = (_Float16)v.z; p[3] = (_Float16)v.w;
    }
}

// All three weight transposes in one launch.
__global__ void convert_wT3_kernel(
    const float* __restrict__ W1, const float* __restrict__ W2, const float* __restrict__ W3,
    _Float16* __restrict__ T1, _Float16* __restrict__ T2, _Float16* __restrict__ T3)
{
    const int z = blockIdx.z;
    const float* W = (z == 0) ? W1 : (z == 1) ? W2 : W3;
    _Float16* T = (z == 0) ? T1 : (z == 1) ? T2 : T3;
    const int K = (z == 0) ? 384 : 512;
    const int N = (z == 2) ? 384 : 512;
    int k = blockIdx.x * 64 + (threadIdx.x & 63);
    int n = blockIdx.y * 4 + (threadIdx.x >> 6);
    if (k < K && n < N) T[(size_t)n * K + k] = (_Float16)W[(size_t)k * N + n];
}

// ---------------- CSR build (by dst) ----------------
__global__ void count_kernel(const int* __restrict__ dst, int* __restrict__ deg, int E)
{
    int e = blockIdx.x * blockDim.x + threadIdx.x;
    if (e < E) atomicAdd(&deg[dst[e]], 1);
}

__global__ __launch_bounds__(256) void block_sum_kernel(
    const int* __restrict__ deg, int* __restrict__ bsum, int Nn)
{
    int gid = blockIdx.x * 256 + threadIdx.x;
    int v = (gid < Nn) ? deg[gid] : 0;
#pragma unroll
    for (int o = 32; o >= 1; o >>= 1) v += __shfl_xor(v, o);
    __shared__ int ws[4];
    if ((threadIdx.x & 63) == 0) ws[threadIdx.x >> 6] = v;
    __syncthreads();
    if (threadIdx.x == 0) bsum[blockIdx.x] = ws[0] + ws[1] + ws[2] + ws[3];
}

// also resets the gather work-queue counters (saves a memset dispatch)
__global__ __launch_bounds__(256) void scan_bsum_kernel(
    const int* __restrict__ bsum, int* __restrict__ bbase, int* __restrict__ ctr, int nb)
{
    __shared__ int s[256];
    const int tid = threadIdx.x;
    int v = (tid < nb) ? bsum[tid] : 0;
    s[tid] = v;
    __syncthreads();
    for (int off = 1; off < 256; off <<= 1) {
        int t = (tid >= off) ? s[tid - off] : 0;
        __syncthreads();
        s[tid] += t;
        __syncthreads();
    }
    if (tid < nb) bbase[tid] = s[tid] - v;
    if (tid < 2) ctr[tid] = 0;
}

__global__ __launch_bounds__(256) void fill_rowptr_kernel(
    const int* __restrict__ deg, const int* __restrict__ bbase,
    int* __restrict__ rowptr, int* __restrict__ cursor, int Nn, int E)
{
    __shared__ int s[256];
    const int tid = threadIdx.x;
    const int gid = blockIdx.x * 256 + tid;
    int v = (gid < Nn) ? deg[gid] : 0;
    s[tid] = v;
    __syncthreads();
    for (int off = 1; off < 256; off <<= 1) {
        int t = (tid >= off) ? s[tid - off] : 0;
        __syncthreads();
        s[tid] += t;
        __syncthreads();
    }
    if (gid < Nn) {
        int r = bbase[blockIdx.x] + s[tid] - v;
        rowptr[gid] = r;
        cursor[gid] = r;
    }
    if (gid == 0) rowptr[Nn] = E;
}

// fill CSR: src index per slot
__global__ void fill_kernel(const int* __restrict__ src, const int* __restrict__ dst,
                            int* __restrict__ cursor, int* __restrict__ eidx, int E)
{
    int e = blockIdx.x * blockDim.x + threadIdx.x;
    if (e < E) {
        int d = dst[e];
        int pos = atomicAdd(&cursor[d], 1);
        eidx[pos] = src[e];
    }
}

// ---------------- gather v9: persistent waves + work queue ----------------
// One wave owns one node (64 lanes x 8 ch = full 512-ch row); waves pull node
// ids from a global atomic counter -> no straggler coupling, no fixed grid
// mapping. Per-edge weight computed inline. Nontemporal out store (consumed
// once by the next GEMM; don't evict h).
__global__ __launch_bounds__(256) void gather_kernel(
    const _Float16* __restrict__ h, const float* __restrict__ a_src,
    const float* __restrict__ a_dst,
    const int* __restrict__ rowptr, const int* __restrict__ eidx,
    const float* __restrict__ bias, _Float16* __restrict__ out,
    int* __restrict__ ctr, int Nn)
{
    const int lane = threadIdx.x & 63;
    const int hd = lane >> 4;
    const _Float16* hb = h + (size_t)lane * 8;

    float bv[8];
    {
        const float* bp = bias + lane * 8;
#pragma unroll
        for (int i = 0; i < 8; i++) bv[i] = bp[i];
    }

    for (;;) {
        int node;
        if (lane == 0) node = atomicAdd(ctr, 1);
        node = __shfl(node, 0);
        if (node >= Nn) break;

        const int beg = rowptr[node];
        const int deg = rowptr[node + 1] - beg;

        const float ad = a_dst[(size_t)node * 4 + hd];

        float acc[8];
#pragma unroll
        for (int i = 0; i < 8; i++) acc[i] = 0.f;
        float dsum = 0.f;

        // virtual self-loop
        {
            const float as = a_src[(size_t)node * 4 + hd];
            half8 hv = *(const half8*)(hb + (size_t)node * HC);
            float l = as + ad; l = l > 0.f ? l : NEG * l;
            const float w = __expf(l);
            dsum += w;
#pragma unroll
            for (int i = 0; i < 8; i++) acc[i] += w * (float)hv[i];
        }

        int e = 0;
        for (; e + 2 <= deg; e += 2) {
            const int s0 = eidx[beg + e];
            const int s1 = eidx[beg + e + 1];
            half8 hv0 = *(const half8*)(hb + (size_t)s0 * HC);
            half8 hv1 = *(const half8*)(hb + (size_t)s1 * HC);
            const float as0 = a_src[(size_t)s0 * 4 + hd];
            const float as1 = a_src[(size_t)s1 * 4 + hd];
            float l0 = as0 + ad; l0 = l0 > 0.f ? l0 : NEG * l0;
            float l1 = as1 + ad; l1 = l1 > 0.f ? l1 : NEG * l1;
            const float w0 = __expf(l0);
            const float w1 = __expf(l1);
            dsum += w0 + w1;
#pragma unroll
            for (int i = 0; i < 8; i++) acc[i] += w0 * (float)hv0[i];
#pragma unroll
            for (int i = 0; i < 8; i++) acc[i] += w1 * (float)hv1[i];
        }
        if (e < deg) {
            const int s0 = eidx[beg + e];
            half8 hv0 = *(const half8*)(hb + (size_t)s0 * HC);
            const float as0 = a_src[(size_t)s0 * 4 + hd];
            float l0 = as0 + ad; l0 = l0 > 0.f ? l0 : NEG * l0;
            const float w0 = __expf(l0);
            dsum += w0;
#pragma unroll
            for (int i = 0; i < 8; i++) acc[i] += w0 * (float)hv0[i];
        }

        const float is = 1.f / dsum;
        half8 ov;
#pragma unroll
        for (int i = 0; i < 8; i++) {
            float o = acc[i] * is + bv[i];
            o = o > 0.f ? o : 0.f;
            ov[i] = (_Float16)o;
        }
        uint4v uv = *(uint4v*)&ov;
        __builtin_nontemporal_store(uv, (uint4v*)(out + (size_t)node * HC + (size_t)lane * 8));
    }
}

extern "C" void kernel_launch(void* const* d_in, const int* in_sizes, int n_in,
                              void* d_out, int out_size, void* d_ws, size_t ws_size,
                              hipStream_t stream)
{
    const float* x   = (const float*)d_in[0];
    const int*   ei  = (const int*)d_in[1];
    const float* W1  = (const float*)d_in[2];
    const float* a1s = (const float*)d_in[3];
    const float* a1d = (const float*)d_in[4];
    const float* b1  = (const float*)d_in[5];
    const float* W2  = (const float*)d_in[6];
    const float* a2s = (const float*)d_in[7];
    const float* a2d = (const float*)d_in[8];
    const float* b2  = (const float*)d_in[9];
    const float* Wfc = (const float*)d_in[10];
    const float* bfc = (const float*)d_in[11];
    float* out = (float*)d_out;

    const int Nn  = in_sizes[0] / 384;        // 50000
    const int E   = in_sizes[1] / 2;          // 500000
    const int IN  = 384;
    const int OUT = in_sizes[11];             // 384
    const int Mp  = ((Nn + 127) / 128) * 128; // 50048
    const int nb  = (Nn + 255) / 256;         // scan blocks (196)

    uint8_t* p = (uint8_t*)d_ws;
    auto alloc = [&](size_t bytes) {
        uint8_t* r = p;
        p += (bytes + 255) & ~(size_t)255;
        return r;
    };
    _Float16* Ah_x = (_Float16*)alloc((size_t)Mp * IN * 2);   // f16 x
    _Float16* Ah_g = (_Float16*)alloc((size_t)Mp * HC * 2);   // gather out (GEMM input)
    _Float16* Hh   = (_Float16*)alloc((size_t)Mp * HC * 2);   // GEMM h out (f16)
    _Float16* Wt1  = (_Float16*)alloc((size_t)HC * IN * 2);
    _Float16* Wt2  = (_Float16*)alloc((size_t)HC * HC * 2);
    _Float16* Wt3  = (_Float16*)alloc((size_t)OUT * HC * 2);
    float* a_src   = (float*)alloc((size_t)Nn * 4 * 4);
    float* a_dst   = (float*)alloc((size_t)Nn * 4 * 4);
    int* deg       = (int*)alloc((size_t)Nn * 4);
    int* rowptr    = (int*)alloc((size_t)(Nn + 1) * 4);
    int* cursor    = (int*)alloc((size_t)Nn * 4);
    int* eidx      = (int*)alloc((size_t)E * 4);
    int* bsum      = (int*)alloc((size_t)nb * 4);
    int* bbase     = (int*)alloc((size_t)nb * 4);
    int* ctr       = (int*)alloc(2 * 4);

    const int* e_src = ei;
    const int* e_dst = ei + E;

    // conversions
    {
        size_t nq = (size_t)Nn * IN / 4;
        convert_x_kernel<<<(nq + 255) / 256, 256, 0, stream>>>(x, Ah_x, nq);
        dim3 gw(8, 128, 3);
        convert_wT3_kernel<<<gw, 256, 0, stream>>>(W1, W2, Wfc, Wt1, Wt2, Wt3);
    }

    // CSR build (parallel scan)
    (void)hipMemsetAsync(deg, 0, Nn * sizeof(int), stream);
    const int eb = (E + 255) / 256;
    count_kernel<<<eb, 256, 0, stream>>>(e_dst, deg, E);
    block_sum_kernel<<<nb, 256, 0, stream>>>(deg, bsum, Nn);
    scan_bsum_kernel<<<1, 256, 0, stream>>>(bsum, bbase, ctr, nb);
    fill_rowptr_kernel<<<nb, 256, 0, stream>>>(deg, bbase, rowptr, cursor, Nn, E);
    fill_kernel<<<eb, 256, 0, stream>>>(e_src, e_dst, cursor, eidx, E);

    const dim3 gg1(HC / 128, Mp / 128);
    const int gb = 2048;   // persistent blocks (4 waves each, work-queue)

    // layer 1
    mfma_gemm<<<gg1, 256, 0, stream>>>(Ah_x, Wt1, Hh, nullptr, nullptr,
                                       a1s, a1d, a_src, a_dst, Nn, HC, IN);
    gather_kernel<<<gb, 256, 0, stream>>>(Hh, a_src, a_dst, rowptr, eidx, b1, Ah_g,
                                          ctr + 0, Nn);

    // layer 2
    mfma_gemm<<<gg1, 256, 0, stream>>>(Ah_g, Wt2, Hh, nullptr, nullptr,
                                       a2s, a2d, a_src, a_dst, Nn, HC, HC);
    gather_kernel<<<gb, 256, 0, stream>>>(Hh, a_src, a_dst, rowptr, eidx, b2, Ah_g,
                                          ctr + 1, Nn);

    // final FC -> fp32 out
    const dim3 gg3(OUT / 128, Mp / 128);
    mfma_gemm<<<gg3, 256, 0, stream>>>(Ah_g, Wt3, nullptr, out, bfc,
                                       nullptr, nullptr, nullptr, nullptr, Nn, OUT, HC);
}

// Round 8
// 527.792 us; speedup vs baseline: 3.3074x; 3.3074x over previous
//
#include <hip/hip_runtime.h>
#include <cfloat>
#include <cstdint>

#define HEADS 4
#define HIDC 128
#define HC 512
#define NEG 0.2f

typedef _Float16 half8 __attribute__((ext_vector_type(8)));
typedef float floatx4 __attribute__((ext_vector_type(4)));

// ---------------- f16 MFMA GEMM ----------------
// C = A[Mp,K] @ Bt[N,K]^T. 128x128 tile, BK=64, 4 waves 2x2, each 64x64 via
// 4x4 mfma_f32_16x16x32_f16 (2 K-slices per iter). XOR-swizzled LDS (linear
// global_load_lds dest + pre-swizzled global source col, same XOR on ds_read).
// XCD-chunk bijective blockIdx swizzle. Nontemporal stores ONLY for Cf (final
// output, consumed by nobody) — Ch (h) is re-read ~11x by gather, keep cached.
// If atts != null (N==512): fuse a_src/a_dst per-head dot into epilogue.
__global__ __launch_bounds__(256) void mfma_gemm(
    const _Float16* __restrict__ A,   // [Mp][K]
    const _Float16* __restrict__ Bt,  // [N][K]
    _Float16* __restrict__ Ch,        // [Mp][N] f16 out (or null)
    float* __restrict__ Cf,           // [M][N] fp32 out (or null)
    const float* __restrict__ bias,   // [N] (with Cf) or null
    const float* __restrict__ atts,   // [HEADS][128] or null
    const float* __restrict__ attd,
    float* __restrict__ a_src,        // [M][4]
    float* __restrict__ a_dst,
    int M, int N, int K)
{
    __shared__ __align__(16) _Float16 As[128 * 64];
    __shared__ __align__(16) _Float16 Bs[128 * 64];

    // ---- bijective XCD swizzle ----
    const int nwg = gridDim.x * gridDim.y;
    int lin = blockIdx.y * gridDim.x + blockIdx.x;
    {
        const int q = nwg >> 3, r = nwg & 7;
        const int xcd = lin & 7, pos = lin >> 3;
        lin = (xcd < r ? xcd * (q + 1) : r * (q + 1) + (xcd - r) * q) + pos;
    }
    const int bx = lin % gridDim.x;
    const int by = lin / gridDim.x;

    const int tid = threadIdx.x;
    const int w = tid >> 6;
    const int lane = tid & 63;
    const int wr = (w >> 1) * 64;
    const int wc = (w & 1) * 64;

    const int rowBase = by * 128;
    const int colBase = bx * 128;

    // staging: per wave 4 stripes of 8 rows (A and B), pre-swizzled source col
    const int strow = lane >> 3;                        // 0..7
    const int sColSw = ((lane & 7) ^ strow) * 8;        // swizzled elem col 0..56

    const _Float16* gaP[4];
    const _Float16* gbP[4];
    _Float16* lA[4];
    _Float16* lB[4];
#pragma unroll
    for (int c = 0; c < 4; c++) {
        const int rr = c * 32 + w * 8;                  // stripe base row
        gaP[c] = A + (size_t)(rowBase + rr + strow) * K + sColSw;
        gbP[c] = Bt + (size_t)(colBase + rr + strow) * K + sColSw;
        lA[c] = &As[rr * 64];
        lB[c] = &Bs[rr * 64];
    }

    floatx4 acc[4][4];
#pragma unroll
    for (int i = 0; i < 4; i++)
#pragma unroll
        for (int j = 0; j < 4; j++) acc[i][j] = {0.f, 0.f, 0.f, 0.f};

    const int q16 = lane >> 4;
    const int l16 = lane & 15;

    for (int k0 = 0; k0 < K; k0 += 64) {
#pragma unroll
        for (int c = 0; c < 4; c++) {
            __builtin_amdgcn_global_load_lds(
                (const __attribute__((address_space(1))) unsigned int*)gaP[c],
                (__attribute__((address_space(3))) unsigned int*)lA[c], 16, 0, 0);
            __builtin_amdgcn_global_load_lds(
                (const __attribute__((address_space(1))) unsigned int*)gbP[c],
                (__attribute__((address_space(3))) unsigned int*)lB[c], 16, 0, 0);
            gaP[c] += 64;
            gbP[c] += 64;
        }
        __syncthreads();

#pragma unroll
        for (int s = 0; s < 2; s++) {
            half8 af[4], bf[4];
#pragma unroll
            for (int i = 0; i < 4; i++) {
                const int r = wr + i * 16 + l16;
                af[i] = *(const half8*)&As[r * 64 + (((s * 4 + q16) ^ (r & 7)) * 8)];
            }
#pragma unroll
            for (int j = 0; j < 4; j++) {
                const int r = wc + j * 16 + l16;
                bf[j] = *(const half8*)&Bs[r * 64 + (((s * 4 + q16) ^ (r & 7)) * 8)];
            }
#pragma unroll
            for (int i = 0; i < 4; i++)
#pragma unroll
                for (int j = 0; j < 4; j++)
                    acc[i][j] = __builtin_amdgcn_mfma_f32_16x16x32_f16(af[i], bf[j], acc[i][j], 0, 0, 0);
        }
        __syncthreads();
    }

    // ---- C stores (C/D layout: col=l16, row=q16*4+r) ----
    if (Ch) {
#pragma unroll
        for (int i = 0; i < 4; i++)
#pragma unroll
            for (int j = 0; j < 4; j++) {
                const int col = colBase + wc + j * 16 + l16;
#pragma unroll
                for (int r = 0; r < 4; r++) {
                    const int row = rowBase + wr + i * 16 + q16 * 4 + r;
                    if (row < M) Ch[(size_t)row * N + col] = (_Float16)acc[i][j][r];
                }
            }
    }
    if (Cf) {
#pragma unroll
        for (int i = 0; i < 4; i++)
#pragma unroll
            for (int j = 0; j < 4; j++) {
                const int col = colBase + wc + j * 16 + l16;
                const float bb = bias ? bias[col] : 0.f;
#pragma unroll
                for (int r = 0; r < 4; r++) {
                    const int row = rowBase + wr + i * 16 + q16 * 4 + r;
                    if (row < M)
                        __builtin_nontemporal_store(acc[i][j][r] + bb,
                                                    &Cf[(size_t)row * N + col]);
                }
            }
    }

    // ---- fused attention coefficients (layers only) ----
    if (atts) {
        float* ps = (float*)As;        // [2][128]
        float* pd = ps + 256;          // [2][128]
        const int head = bx;
        float as[4], ad[4];
#pragma unroll
        for (int j = 0; j < 4; j++) {
            const int cl = wc + j * 16 + l16;
            as[j] = atts[head * HIDC + cl];
            ad[j] = attd[head * HIDC + cl];
        }
#pragma unroll
        for (int i = 0; i < 4; i++) {
#pragma unroll
            for (int r = 0; r < 4; r++) {
                float s_ = acc[i][0][r] * as[0] + acc[i][1][r] * as[1]
                         + acc[i][2][r] * as[2] + acc[i][3][r] * as[3];
                float d_ = acc[i][0][r] * ad[0] + acc[i][1][r] * ad[1]
                         + acc[i][2][r] * ad[2] + acc[i][3][r] * ad[3];
#pragma unroll
                for (int mk = 1; mk <= 8; mk <<= 1) {
                    s_ += __shfl_xor(s_, mk);
                    d_ += __shfl_xor(d_, mk);
                }
                if (l16 == 0) {
                    const int rloc = wr + i * 16 + q16 * 4 + r;
                    ps[(wc >> 6) * 128 + rloc] = s_;
                    pd[(wc >> 6) * 128 + rloc] = d_;
                }
            }
        }
        __syncthreads();
        if (tid < 128) {
            const int row = rowBase + tid;
            if (row < M) {
                a_src[(size_t)row * 4 + head] = ps[tid] + ps[128 + tid];
                a_dst[(size_t)row * 4 + head] = pd[tid] + pd[128 + tid];
            }
        }
    }
}

// ---------------- dtype conversion ----------------
__global__ void convert_x_kernel(const float* __restrict__ x, _Float16* __restrict__ o, size_t nquads)
{
    size_t i = (size_t)blockIdx.x * blockDim.x + threadIdx.x;
    if (i < nquads) {
        float4 v = *(const float4*)(x + i * 4);
        _Float16* p = o + i * 4;
        p[0] = (_Float16)v.x; p[1] = (_Float16)v.y;
        p[2] = (_Float16)v.z; p[3] = (_Float16)v.w;
    }
}

// All three weight transposes in one launch.
__global__ void convert_wT3_kernel(
    const float* __restrict__ W1, const float* __restrict__ W2, const float* __restrict__ W3,
    _Float16* __restrict__ T1, _Float16* __restrict__ T2, _Float16* __restrict__ T3)
{
    const int z = blockIdx.z;
    const float* W = (z == 0) ? W1 : (z == 1) ? W2 : W3;
    _Float16* T = (z == 0) ? T1 : (z == 1) ? T2 : T3;
    const int K = (z == 0) ? 384 : 512;
    const int N = (z == 2) ? 384 : 512;
    int k = blockIdx.x * 64 + (threadIdx.x & 63);
    int n = blockIdx.y * 4 + (threadIdx.x >> 6);
    if (k < K && n < N) T[(size_t)n * K + k] = (_Float16)W[(size_t)k * N + n];
}

// ---------------- CSR build (by dst) ----------------
__global__ void count_kernel(const int* __restrict__ dst, int* __restrict__ deg, int E)
{
    int e = blockIdx.x * blockDim.x + threadIdx.x;
    if (e < E) atomicAdd(&deg[dst[e]], 1);
}

__global__ __launch_bounds__(256) void block_sum_kernel(
    const int* __restrict__ deg, int* __restrict__ bsum, int Nn)
{
    int gid = blockIdx.x * 256 + threadIdx.x;
    int v = (gid < Nn) ? deg[gid] : 0;
#pragma unroll
    for (int o = 32; o >= 1; o >>= 1) v += __shfl_xor(v, o);
    __shared__ int ws[4];
    if ((threadIdx.x & 63) == 0) ws[threadIdx.x >> 6] = v;
    __syncthreads();
    if (threadIdx.x == 0) bsum[blockIdx.x] = ws[0] + ws[1] + ws[2] + ws[3];
}

__global__ __launch_bounds__(256) void scan_bsum_kernel(
    const int* __restrict__ bsum, int* __restrict__ bbase, int nb)
{
    __shared__ int s[256];
    const int tid = threadIdx.x;
    int v = (tid < nb) ? bsum[tid] : 0;
    s[tid] = v;
    __syncthreads();
    for (int off = 1; off < 256; off <<= 1) {
        int t = (tid >= off) ? s[tid - off] : 0;
        __syncthreads();
        s[tid] += t;
        __syncthreads();
    }
    if (tid < nb) bbase[tid] = s[tid] - v;
}

__global__ __launch_bounds__(256) void fill_rowptr_kernel(
    const int* __restrict__ deg, const int* __restrict__ bbase,
    int* __restrict__ rowptr, int* __restrict__ cursor, int Nn, int E)
{
    __shared__ int s[256];
    const int tid = threadIdx.x;
    const int gid = blockIdx.x * 256 + tid;
    int v = (gid < Nn) ? deg[gid] : 0;
    s[tid] = v;
    __syncthreads();
    for (int off = 1; off < 256; off <<= 1) {
        int t = (tid >= off) ? s[tid - off] : 0;
        __syncthreads();
        s[tid] += t;
        __syncthreads();
    }
    if (gid < Nn) {
        int r = bbase[blockIdx.x] + s[tid] - v;
        rowptr[gid] = r;
        cursor[gid] = r;
    }
    if (gid == 0) rowptr[Nn] = E;
}

// fill CSR: src index per slot
__global__ void fill_kernel(const int* __restrict__ src, const int* __restrict__ dst,
                            int* __restrict__ cursor, int* __restrict__ eidx, int E)
{
    int e = blockIdx.x * blockDim.x + threadIdx.x;
    if (e < E) {
        int d = dst[e];
        int pos = atomicAdd(&cursor[d], 1);
        eidx[pos] = src[e];
    }
}

// ---------------- gather (Round-1 proven form): wave-per-node ----------------
// One wave owns one node: 64 lanes x 8 ch = 512 channels = full h row.
// Per-edge softmax weight computed inline (a_src gather + leaky + exp).
// Denominator needs NO reduction: all 16 lanes of a head accumulate the
// identical per-edge weight. No LDS, no barriers, fixed node mapping.
__global__ __launch_bounds__(256) void gather_kernel(
    const _Float16* __restrict__ h, const float* __restrict__ a_src,
    const float* __restrict__ a_dst,
    const int* __restrict__ rowptr, const int* __restrict__ eidx,
    const float* __restrict__ bias, _Float16* __restrict__ out, int Nn)
{
    const int wv = __builtin_amdgcn_readfirstlane(threadIdx.x >> 6);
    const int node = blockIdx.x * 4 + wv;
    if (node >= Nn) return;
    const int lane = threadIdx.x & 63;
    const int hd = lane >> 4;

    const int beg = rowptr[node];
    const int deg = rowptr[node + 1] - beg;

    const float ad = a_dst[(size_t)node * 4 + hd];
    const _Float16* hb = h + (size_t)lane * 8;

    float acc[8];
#pragma unroll
    for (int i = 0; i < 8; i++) acc[i] = 0.f;
    float dsum = 0.f;

    // virtual self-loop
    {
        const float as = a_src[(size_t)node * 4 + hd];
        half8 hv = *(const half8*)(hb + (size_t)node * HC);
        float l = as + ad; l = l > 0.f ? l : NEG * l;
        const float w = __expf(l);
        dsum += w;
#pragma unroll
        for (int i = 0; i < 8; i++) acc[i] += w * (float)hv[i];
    }

    int e = 0;
    for (; e + 2 <= deg; e += 2) {
        const int s0 = eidx[beg + e];
        const int s1 = eidx[beg + e + 1];
        half8 hv0 = *(const half8*)(hb + (size_t)s0 * HC);
        half8 hv1 = *(const half8*)(hb + (size_t)s1 * HC);
        const float as0 = a_src[(size_t)s0 * 4 + hd];
        const float as1 = a_src[(size_t)s1 * 4 + hd];
        float l0 = as0 + ad; l0 = l0 > 0.f ? l0 : NEG * l0;
        float l1 = as1 + ad; l1 = l1 > 0.f ? l1 : NEG * l1;
        const float w0 = __expf(l0);
        const float w1 = __expf(l1);
        dsum += w0 + w1;
#pragma unroll
        for (int i = 0; i < 8; i++) acc[i] += w0 * (float)hv0[i];
#pragma unroll
        for (int i = 0; i < 8; i++) acc[i] += w1 * (float)hv1[i];
    }
    if (e < deg) {
        const int s0 = eidx[beg + e];
        half8 hv0 = *(const half8*)(hb + (size_t)s0 * HC);
        const float as0 = a_src[(size_t)s0 * 4 + hd];
        float l0 = as0 + ad; l0 = l0 > 0.f ? l0 : NEG * l0;
        const float w0 = __expf(l0);
        dsum += w0;
#pragma unroll
        for (int i = 0; i < 8; i++) acc[i] += w0 * (float)hv0[i];
    }

    const float is = 1.f / dsum;
    const float* bp = bias + lane * 8;
    half8 ov;
#pragma unroll
    for (int i = 0; i < 8; i++) {
        float o = acc[i] * is + bp[i];
        o = o > 0.f ? o : 0.f;
        ov[i] = (_Float16)o;
    }
    *(half8*)(out + (size_t)node * HC + (size_t)lane * 8) = ov;
}

extern "C" void kernel_launch(void* const* d_in, const int* in_sizes, int n_in,
                              void* d_out, int out_size, void* d_ws, size_t ws_size,
                              hipStream_t stream)
{
    const float* x   = (const float*)d_in[0];
    const int*   ei  = (const int*)d_in[1];
    const float* W1  = (const float*)d_in[2];
    const float* a1s = (const float*)d_in[3];
    const float* a1d = (const float*)d_in[4];
    const float* b1  = (const float*)d_in[5];
    const float* W2  = (const float*)d_in[6];
    const float* a2s = (const float*)d_in[7];
    const float* a2d = (const float*)d_in[8];
    const float* b2  = (const float*)d_in[9];
    const float* Wfc = (const float*)d_in[10];
    const float* bfc = (const float*)d_in[11];
    float* out = (float*)d_out;

    const int Nn  = in_sizes[0] / 384;        // 50000
    const int E   = in_sizes[1] / 2;          // 500000
    const int IN  = 384;
    const int OUT = in_sizes[11];             // 384
    const int Mp  = ((Nn + 127) / 128) * 128; // 50048
    const int nb  = (Nn + 255) / 256;         // scan blocks (196)

    uint8_t* p = (uint8_t*)d_ws;
    auto alloc = [&](size_t bytes) {
        uint8_t* r = p;
        p += (bytes + 255) & ~(size_t)255;
        return r;
    };
    _Float16* Ah_x = (_Float16*)alloc((size_t)Mp * IN * 2);   // f16 x
    _Float16* Ah_g = (_Float16*)alloc((size_t)Mp * HC * 2);   // gather out (GEMM input)
    _Float16* Hh   = (_Float16*)alloc((size_t)Mp * HC * 2);   // GEMM h out (f16)
    _Float16* Wt1  = (_Float16*)alloc((size_t)HC * IN * 2);
    _Float16* Wt2  = (_Float16*)alloc((size_t)HC * HC * 2);
    _Float16* Wt3  = (_Float16*)alloc((size_t)OUT * HC * 2);
    float* a_src   = (float*)alloc((size_t)Nn * 4 * 4);
    float* a_dst   = (float*)alloc((size_t)Nn * 4 * 4);
    int* deg       = (int*)alloc((size_t)Nn * 4);
    int* rowptr    = (int*)alloc((size_t)(Nn + 1) * 4);
    int* cursor    = (int*)alloc((size_t)Nn * 4);
    int* eidx      = (int*)alloc((size_t)E * 4);
    int* bsum      = (int*)alloc((size_t)nb * 4);
    int* bbase     = (int*)alloc((size_t)nb * 4);

    const int* e_src = ei;
    const int* e_dst = ei + E;

    // conversions
    {
        size_t nq = (size_t)Nn * IN / 4;
        convert_x_kernel<<<(nq + 255) / 256, 256, 0, stream>>>(x, Ah_x, nq);
        dim3 gw(8, 128, 3);
        convert_wT3_kernel<<<gw, 256, 0, stream>>>(W1, W2, Wfc, Wt1, Wt2, Wt3);
    }

    // CSR build (parallel scan)
    (void)hipMemsetAsync(deg, 0, Nn * sizeof(int), stream);
    const int eb = (E + 255) / 256;
    count_kernel<<<eb, 256, 0, stream>>>(e_dst, deg, E);
    block_sum_kernel<<<nb, 256, 0, stream>>>(deg, bsum, Nn);
    scan_bsum_kernel<<<1, 256, 0, stream>>>(bsum, bbase, nb);
    fill_rowptr_kernel<<<nb, 256, 0, stream>>>(deg, bbase, rowptr, cursor, Nn, E);
    fill_kernel<<<eb, 256, 0, stream>>>(e_src, e_dst, cursor, eidx, E);

    const dim3 gg1(HC / 128, Mp / 128);
    const int gb = (Nn + 3) / 4;   // gather blocks (4 waves = 4 nodes each)

    // layer 1
    mfma_gemm<<<gg1, 256, 0, stream>>>(Ah_x, Wt1, Hh, nullptr, nullptr,
                                       a1s, a1d, a_src, a_dst, Nn, HC, IN);
    gather_kernel<<<gb, 256, 0, stream>>>(Hh, a_src, a_dst, rowptr, eidx, b1, Ah_g, Nn);

    // layer 2
    mfma_gemm<<<gg1, 256, 0, stream>>>(Ah_g, Wt2, Hh, nullptr, nullptr,
                                       a2s, a2d, a_src, a_dst, Nn, HC, HC);
    gather_kernel<<<gb, 256, 0, stream>>>(Hh, a_src, a_dst, rowptr, eidx, b2, Ah_g, Nn);

    // final FC -> fp32 out
    const dim3 gg3(OUT / 128, Mp / 128);
    mfma_gemm<<<gg3, 256, 0, stream>>>(Ah_g, Wt3, nullptr, out, bfc,
                                       nullptr, nullptr, nullptr, nullptr, Nn, OUT, HC);
}